// Round 4
// baseline (182.080 us; speedup 1.0000x reference)
//
#include <hip/hip_runtime.h>

// x = [32, 3, 512, 512] fp32, scale_factors = [2] fp32. Output same shape as x.
#define BD 32
#define CD 3
#define HD 512
#define WD 512
#define TH 8           // output rows per block
#define NSLOT (2 * TH) // staged input corner-rows (iy0c, iy1c per output row)

typedef __attribute__((address_space(1))) const void GV;
typedef __attribute__((address_space(3))) void LV;

// Separable bilinear grid-sample (diagonal affine, zeros padding,
// align_corners=False).
// Phase A: async DMA (global_load_lds, width 16) of the 16 raw corner rows
//          into LDS — 8 outstanding loads/thread, ZERO VGPR round-trip.
// Phase B: fused H-interp + W-gather from LDS, ds_read2-friendly base/base+1
//          access with remapped edge weights (exact for all scales).
__global__ __launch_bounds__(256) void stn_kernel(const float* __restrict__ x,
                                                  const float* __restrict__ sf,
                                                  float* __restrict__ out) {
    __shared__ float xh[NSLOT][WD];  // 32 KB raw staged rows

    const int plane = blockIdx.x;       // 0..95  (b*C + c)
    const int h0    = blockIdx.y * TH;  // strip start
    const float sx = sf[0];
    const float sy = sf[1];

    const int t = threadIdx.x;  // 0..255
    const int p = t >> 7;       // which corner this thread stages (0/1)
    const int l = t & 127;      // 128-wide column group: floats [4l, 4l+4)

    const float* xp = x + (long long)plane * HD * WD;

    // ---- phase A: row params + async staging of raw corner rows ----
    float fy0[TH], fy1[TH];
#pragma unroll
    for (int s = 0; s < TH; ++s) {
        int   h    = h0 + s;
        float ysn  = (2.0f * (float)h + 1.0f) / (float)HD - 1.0f;
        float iy   = ((sy * ysn + 1.0f) * (float)HD - 1.0f) * 0.5f;
        float iy0f = floorf(iy);
        float wy1  = iy - iy0f;
        int   iy0  = (int)iy0f;
        int   iy1  = iy0 + 1;
        fy0[s] = (iy0 >= 0 && iy0 < HD) ? (1.0f - wy1) : 0.0f;
        fy1[s] = (iy1 >= 0 && iy1 < HD) ? wy1 : 0.0f;
        int iy0c = min(max(iy0, 0), HD - 1);
        int iy1c = min(max(iy1, 0), HD - 1);
        int rowc = p ? iy1c : iy0c;
        // wave-uniform LDS base + lane*16: lanes of each wave cover a
        // contiguous 1 KB half of slot (2s+p). Valid global_load_lds layout.
        const float* src = xp + (long long)rowc * WD + (l << 2);
        __builtin_amdgcn_global_load_lds((GV*)src, (LV*)&xh[2 * s + p][l << 2],
                                         16, 0, 0);
    }
    __syncthreads();  // drains vmcnt + barrier

    // ---- phase B: per-column params (2 cols/thread), exact edge remap ----
    float wa[2], wb[2];
    int   basec[2];
#pragma unroll
    for (int j = 0; j < 2; ++j) {
        int   w    = 2 * t + j;
        float xsn  = (2.0f * (float)w + 1.0f) / (float)WD - 1.0f;
        float ix   = ((sx * xsn + 1.0f) * (float)WD - 1.0f) * 0.5f;
        float ix0f = floorf(ix);
        float wx1  = ix - ix0f;
        int   ix0  = (int)ix0f;
        int   ix1  = ix0 + 1;
        float fx0  = (ix0 >= 0 && ix0 < WD) ? (1.0f - wx1) : 0.0f;
        float fx1  = (ix1 >= 0 && ix1 < WD) ? wx1 : 0.0f;
        int   base = min(max(ix0, 0), WD - 2);
        basec[j] = base;
        // weight for xh[base] / xh[base+1]; handles both clamp directions
        wa[j] = (ix0 == base) ? fx0 : ((ix1 == base) ? fx1 : 0.0f);
        wb[j] = (ix0 == base + 1) ? fx0 : ((ix1 == base + 1) ? fx1 : 0.0f);
    }

    float* outp = out + ((long long)plane * HD + h0) * WD + 2 * t;
#pragma unroll
    for (int r = 0; r < TH; ++r) {
        float2 o;
#pragma unroll
        for (int j = 0; j < 2; ++j) {
            int   b   = basec[j];
            float v0  = xh[2 * r][b];      // ds_read2_b32 pair
            float v1  = xh[2 * r][b + 1];
            float u0  = xh[2 * r + 1][b];  // ds_read2_b32 pair
            float u1  = xh[2 * r + 1][b + 1];
            float hv0 = v0 * fy0[r] + u0 * fy1[r];
            float hv1 = v1 * fy0[r] + u1 * fy1[r];
            ((float*)&o)[j] = hv0 * wa[j] + hv1 * wb[j];
        }
        *(float2*)(outp + (long long)r * WD) = o;
    }
}

extern "C" void kernel_launch(void* const* d_in, const int* in_sizes, int n_in,
                              void* d_out, int out_size, void* d_ws, size_t ws_size,
                              hipStream_t stream) {
    const float* x  = (const float*)d_in[0];
    const float* sf = (const float*)d_in[1];
    float* out      = (float*)d_out;

    dim3 grid(BD * CD, HD / TH);  // 96 x 64; strip neighbors (±96 blocks) land
                                  // on the same XCD (96 % 8 == 0) for L2 reuse
    stn_kernel<<<grid, 256, 0, stream>>>(x, sf, out);
}